// Round 1
// baseline (1044.906 us; speedup 1.0000x reference)
//
#include <hip/hip_runtime.h>

typedef unsigned short ushort_t;
typedef __bf16 bf16x8 __attribute__((ext_vector_type(8)));
typedef float f32x4 __attribute__((ext_vector_type(4)));

#define GN 10000
#define GE 640000
#define INC 256
#define HID 128
#define OUTC 64

// ---------------- workspace layout (bytes, all 256-aligned) ----------------
constexpr size_t OFF_WTT   = 0;          // bf16 Wt^T [256][10000]       5,120,000
constexpr size_t OFF_P     = 5120000;    // fp32 partials [4][10048][256] 41,156,608
constexpr size_t OFF_H     = 46276608;   // fp32 h  [10000][256]         10,240,000
constexpr size_t OFF_TX1   = 56516608;   // fp32 tx1[10000][256]         10,240,000
constexpr size_t OFF_H2    = 66756608;   // fp32 h2 [10000][128]          5,120,000
constexpr size_t OFF_TX2   = 71876608;   // fp32 tx2[10000][128]          5,120,000
constexpr size_t OFF_DEG   = 76996608;   // int outdeg [10240]               40,960
constexpr size_t OFF_INDEG = 77037568;   // int indeg  [10240]               40,960
constexpr size_t OFF_CUR   = 77078528;   // int cursor [10240]               40,960
constexpr size_t OFF_RP    = 77119488;   // int row_ptr[10001]               40,960
constexpr size_t OFF_DINV  = 77160448;   // float dinv [10000]               40,960
constexpr size_t OFF_CSRC  = 77201408;   // int   csr_src [E]             2,560,000
constexpr size_t OFF_CSW   = 79761408;   // float csr_w   [E]             2,560,000
// total ~82.3 MB

__device__ __forceinline__ ushort_t f2bf(float f) {
  unsigned int u = __float_as_uint(f);
  u += 0x7fffu + ((u >> 16) & 1u);   // RNE
  return (ushort_t)(u >> 16);
}

// ---------------- zero the three atomic-counter arrays ----------------
__global__ __launch_bounds__(256) void zero_ints(int* __restrict__ p) {
  p[blockIdx.x * 256 + threadIdx.x] = 0;   // 30720 ints: outdeg|indeg|cursor
}

// ---------------- Wt [10000][256] f32 -> Wt^T [256][10000] bf16 ----------------
__global__ __launch_bounds__(256) void transpose_wt(const float* __restrict__ Wt,
                                                    ushort_t* __restrict__ WtT) {
  __shared__ float tile[32][33];
  const int tx = threadIdx.x & 31, ty = threadIdx.x >> 5;   // 32 x 8
  const int k0 = blockIdx.x * 32, c0 = blockIdx.y * 32;
#pragma unroll
  for (int j = 0; j < 4; ++j) {
    const int k = k0 + ty + j * 8;
    if (k < GN) tile[ty + j * 8][tx] = Wt[(size_t)k * INC + c0 + tx];
  }
  __syncthreads();
#pragma unroll
  for (int j = 0; j < 4; ++j) {
    const int c = c0 + ty + j * 8;
    const int k = k0 + tx;
    if (k < GN) WtT[(size_t)c * GN + k] = f2bf(tile[tx][ty + j * 8]);
  }
}

// ---------------- degree counts ----------------
__global__ __launch_bounds__(256) void count_deg(const int* __restrict__ src,
                                                 const int* __restrict__ dst,
                                                 int* __restrict__ outdeg,
                                                 int* __restrict__ indeg) {
  const int e = blockIdx.x * 256 + threadIdx.x;
  atomicAdd(&outdeg[src[e]], 1);
  atomicAdd(&indeg[dst[e]], 1);
}

__global__ __launch_bounds__(256) void dinv_kernel(const int* __restrict__ outdeg,
                                                   float* __restrict__ dinv) {
  const int i = blockIdx.x * 256 + threadIdx.x;
  if (i < GN) {
    const int d = outdeg[i];
    dinv[i] = (d > 0) ? rsqrtf((float)d) : 0.f;
  }
}

// ---------------- exclusive scan of indeg -> row_ptr[0..10000] ----------------
__global__ __launch_bounds__(1024) void scan_kernel(const int* __restrict__ indeg,
                                                    int* __restrict__ row_ptr) {
  __shared__ int sdata[1024];
  const int t = threadIdx.x;
  const int base = t * 10;
  int loc[10];
  int s = 0;
#pragma unroll
  for (int j = 0; j < 10; ++j) {
    const int idx = base + j;
    const int v = (idx < GN) ? indeg[idx] : 0;
    loc[j] = v;
    s += v;
  }
  sdata[t] = s;
  __syncthreads();
  for (int off = 1; off < 1024; off <<= 1) {
    int v = 0;
    if (t >= off) v = sdata[t - off];
    __syncthreads();
    if (t >= off) sdata[t] += v;
    __syncthreads();
  }
  int run = sdata[t] - s;   // exclusive prefix
#pragma unroll
  for (int j = 0; j < 10; ++j) {
    const int idx = base + j;
    if (idx <= GN) row_ptr[idx] = run;
    if (idx < GN) run += loc[j];
  }
}

// ---------------- CSR fill (by dst) ----------------
__global__ __launch_bounds__(256) void fill_csr(const int* __restrict__ src,
                                                const int* __restrict__ dst,
                                                const float* __restrict__ dinv,
                                                const int* __restrict__ row_ptr,
                                                int* __restrict__ cursor,
                                                int* __restrict__ csr_src,
                                                float* __restrict__ csr_w) {
  const int e = blockIdx.x * 256 + threadIdx.x;
  const int s = src[e];
  const int d = dst[e];
  const float w = -dinv[s] * dinv[d];
  const int pos = atomicAdd(&cursor[d], 1);
  const int slot = row_ptr[d] + pos;
  csr_src[slot] = s;
  csr_w[slot] = w;
}

// ---------------- GEMM1: h_partial = x @ Wt  (bf16 MFMA, split-K=4) ----------------
// grid (157, 4), block 256. Tile: BM=64 x BN=256, BK=64. LDS 46 KB.
__global__ __launch_bounds__(256) void gemm1_kernel(const float* __restrict__ x,
                                                    const ushort_t* __restrict__ WtT,
                                                    float* __restrict__ P) {
  constexpr int LDK = 72;   // 64 + 8 bf16 pad (16 B) -> 2-way-free LDS banking
  __shared__ __align__(16) ushort_t As[64 * LDK];
  __shared__ __align__(16) ushort_t Bs[256 * LDK];
  const int t = threadIdx.x;
  const int rowbase = blockIdx.x * 64;
  const int ks = blockIdx.y;
  const int kbeg = ks * 2560;
  const int kend = min(kbeg + 2560, GN);
  const int nit = (kend - kbeg + 63) >> 6;
  const int lane = t & 63, wave = t >> 6;
  const int m16 = lane & 15, quad = lane >> 4;

  f32x4 acc[4][4];
#pragma unroll
  for (int i = 0; i < 4; ++i)
#pragma unroll
    for (int j = 0; j < 4; ++j) acc[i][j] = {0.f, 0.f, 0.f, 0.f};

  const int ar = t >> 4;            // 0..15  (A row group)
  const int ak = (t & 15) << 2;     // 0..60  (A k offset, float4)
  const int bn = t >> 3;            // 0..31  (B row group)
  const int bk = (t & 7) << 3;      // 0..56  (B k offset, 8 bf16)

  for (int it = 0; it < nit; ++it) {
    const int k0 = kbeg + (it << 6);
    // stage A: x fp32 -> bf16 LDS (64 rows x 64 k)
#pragma unroll
    for (int i = 0; i < 4; ++i) {
      const int r = ar + i * 16;
      const int row = rowbase + r;
      const int gk = k0 + ak;
      float4 v = make_float4(0.f, 0.f, 0.f, 0.f);
      if (row < GN && gk < kend) v = *(const float4*)(x + (size_t)row * GN + gk);
      ushort4 o = make_ushort4(f2bf(v.x), f2bf(v.y), f2bf(v.z), f2bf(v.w));
      *reinterpret_cast<ushort4*>(&As[r * LDK + ak]) = o;
    }
    // stage B: Wt^T bf16 (256 rows x 64 k)
#pragma unroll
    for (int i = 0; i < 8; ++i) {
      const int n = bn + i * 32;
      const int gk = k0 + bk;
      uint4 v = make_uint4(0u, 0u, 0u, 0u);
      if (gk < kend) v = *(const uint4*)(WtT + (size_t)n * GN + gk);
      *reinterpret_cast<uint4*>(&Bs[n * LDK + bk]) = v;
    }
    __syncthreads();
#pragma unroll
    for (int hh = 0; hh < 2; ++hh) {
      const int kk = hh * 32 + quad * 8;
      bf16x8 a[4], b[4];
#pragma unroll
      for (int mi = 0; mi < 4; ++mi)
        a[mi] = *reinterpret_cast<const bf16x8*>(&As[(mi * 16 + m16) * LDK + kk]);
#pragma unroll
      for (int ni = 0; ni < 4; ++ni)
        b[ni] = *reinterpret_cast<const bf16x8*>(&Bs[(wave * 64 + ni * 16 + m16) * LDK + kk]);
#pragma unroll
      for (int mi = 0; mi < 4; ++mi)
#pragma unroll
        for (int ni = 0; ni < 4; ++ni)
          acc[mi][ni] = __builtin_amdgcn_mfma_f32_16x16x32_bf16(a[mi], b[ni], acc[mi][ni], 0, 0, 0);
    }
    __syncthreads();
  }
  // store partial tile: C layout col=lane&15, row=quad*4+reg
#pragma unroll
  for (int mi = 0; mi < 4; ++mi)
#pragma unroll
    for (int ni = 0; ni < 4; ++ni) {
      const int col = wave * 64 + ni * 16 + m16;
      const int row0 = rowbase + mi * 16 + quad * 4;
      float* p = P + ((size_t)ks * 10048 + row0) * 256 + col;
#pragma unroll
      for (int r = 0; r < 4; ++r) p[(size_t)r * 256] = acc[mi][ni][r];
    }
}

// ---------------- combine split-K partials + bias + relu -> h ----------------
__global__ __launch_bounds__(256) void combine_kernel(const float* __restrict__ P,
                                                      const float* __restrict__ bt,
                                                      float* __restrict__ h) {
  const int tid = blockIdx.x * 256 + threadIdx.x;
  const int i = tid >> 6;
  const int c = (tid & 63) << 2;
  const size_t stride = (size_t)10048 * 256;
  const size_t base = (size_t)i * 256 + c;
  const float4 p0 = *(const float4*)(P + 0 * stride + base);
  const float4 p1 = *(const float4*)(P + 1 * stride + base);
  const float4 p2 = *(const float4*)(P + 2 * stride + base);
  const float4 p3 = *(const float4*)(P + 3 * stride + base);
  const float4 bv = *(const float4*)(bt + c);
  float4 o;
  o.x = fmaxf(p0.x + p1.x + p2.x + p3.x + bv.x, 0.f);
  o.y = fmaxf(p0.y + p1.y + p2.y + p3.y + bv.y, 0.f);
  o.z = fmaxf(p0.z + p1.z + p2.z + p3.z + bv.z, 0.f);
  o.w = fmaxf(p0.w + p1.w + p2.w + p3.w + bv.w, 0.f);
  *(float4*)(h + base) = o;
}

// ---------------- SpMM: tx[d] = sum_{e: dst=d} w_e * h[src_e]  (CSR, conflict-free) ----------------
template <int C, int NPB>
__global__ __launch_bounds__(256) void spmm_kernel(const float* __restrict__ h,
                                                   const int* __restrict__ row_ptr,
                                                   const int* __restrict__ csr_src,
                                                   const float* __restrict__ csr_w,
                                                   float* __restrict__ tx) {
  const int d = blockIdx.x * NPB + (int)(threadIdx.x / C);
  const int c = threadIdx.x % C;
  const int beg = row_ptr[d];
  const int end = row_ptr[d + 1];
  float acc = 0.f;
#pragma unroll 4
  for (int j = beg; j < end; ++j) {
    const int s = csr_src[j];
    const float w = csr_w[j];
    acc = fmaf(w, h[(size_t)s * C + c], acc);
  }
  tx[(size_t)d * C + c] = acc;
}

// ---------------- dense conv1: h2 = relu(h@W0 + tx1@W1 + b1) ----------------
__global__ __launch_bounds__(256) void dense1_kernel(const float* __restrict__ h,
                                                     const float* __restrict__ tx,
                                                     const float* __restrict__ W0,
                                                     const float* __restrict__ W1,
                                                     const float* __restrict__ b,
                                                     float* __restrict__ out) {
  const int t = threadIdx.x;
  const int cq = (t & 31) << 2;            // 0..124
  const int rq = t >> 5;                   // 0..7
  const int row0 = blockIdx.x * 32 + rq * 4;
  int rowc[4];
#pragma unroll
  for (int r = 0; r < 4; ++r) rowc[r] = min(row0 + r, GN - 1);
  float acc[4][4] = {};
  for (int k = 0; k < INC; k += 4) {
    const float4 w0 = *(const float4*)(W0 + (size_t)(k + 0) * HID + cq);
    const float4 w1 = *(const float4*)(W0 + (size_t)(k + 1) * HID + cq);
    const float4 w2 = *(const float4*)(W0 + (size_t)(k + 2) * HID + cq);
    const float4 w3 = *(const float4*)(W0 + (size_t)(k + 3) * HID + cq);
#pragma unroll
    for (int r = 0; r < 4; ++r) {
      const float4 hv = *(const float4*)(h + (size_t)rowc[r] * INC + k);
      acc[r][0] += hv.x * w0.x + hv.y * w1.x + hv.z * w2.x + hv.w * w3.x;
      acc[r][1] += hv.x * w0.y + hv.y * w1.y + hv.z * w2.y + hv.w * w3.y;
      acc[r][2] += hv.x * w0.z + hv.y * w1.z + hv.z * w2.z + hv.w * w3.z;
      acc[r][3] += hv.x * w0.w + hv.y * w1.w + hv.z * w2.w + hv.w * w3.w;
    }
  }
  for (int k = 0; k < INC; k += 4) {
    const float4 w0 = *(const float4*)(W1 + (size_t)(k + 0) * HID + cq);
    const float4 w1 = *(const float4*)(W1 + (size_t)(k + 1) * HID + cq);
    const float4 w2 = *(const float4*)(W1 + (size_t)(k + 2) * HID + cq);
    const float4 w3 = *(const float4*)(W1 + (size_t)(k + 3) * HID + cq);
#pragma unroll
    for (int r = 0; r < 4; ++r) {
      const float4 hv = *(const float4*)(tx + (size_t)rowc[r] * INC + k);
      acc[r][0] += hv.x * w0.x + hv.y * w1.x + hv.z * w2.x + hv.w * w3.x;
      acc[r][1] += hv.x * w0.y + hv.y * w1.y + hv.z * w2.y + hv.w * w3.y;
      acc[r][2] += hv.x * w0.z + hv.y * w1.z + hv.z * w2.z + hv.w * w3.z;
      acc[r][3] += hv.x * w0.w + hv.y * w1.w + hv.z * w2.w + hv.w * w3.w;
    }
  }
#pragma unroll
  for (int r = 0; r < 4; ++r) {
    const int row = row0 + r;
    if (row < GN) {
      float4 o;
      o.x = fmaxf(acc[r][0] + b[cq + 0], 0.f);
      o.y = fmaxf(acc[r][1] + b[cq + 1], 0.f);
      o.z = fmaxf(acc[r][2] + b[cq + 2], 0.f);
      o.w = fmaxf(acc[r][3] + b[cq + 3], 0.f);
      *(float4*)(out + (size_t)row * HID + cq) = o;
    }
  }
}

// ---------------- dense conv_mu / conv_logstd fused: out = [mu | logstd] ----------------
__global__ __launch_bounds__(256) void dense2_kernel(const float* __restrict__ h2,
                                                     const float* __restrict__ tx2,
                                                     const float* __restrict__ W0mu,
                                                     const float* __restrict__ W1mu,
                                                     const float* __restrict__ bmu,
                                                     const float* __restrict__ W0ls,
                                                     const float* __restrict__ W1ls,
                                                     const float* __restrict__ bls,
                                                     float* __restrict__ out) {
  const int t = threadIdx.x;
  const int cq = (t & 31) << 2;           // 0..124 across [mu(64) | ls(64)]
  const int rq = t >> 5;
  const int row0 = blockIdx.x * 32 + rq * 4;
  const bool is_mu = (cq < OUTC);
  const int cc = cq & (OUTC - 1);
  const float* Wa = is_mu ? W0mu : W0ls;
  const float* Wb = is_mu ? W1mu : W1ls;
  const float* bb = is_mu ? bmu : bls;
  float* outp = out + (is_mu ? (size_t)0 : (size_t)GN * OUTC);
  int rowc[4];
#pragma unroll
  for (int r = 0; r < 4; ++r) rowc[r] = min(row0 + r, GN - 1);
  float acc[4][4] = {};
  for (int k = 0; k < HID; k += 4) {
    const float4 w0 = *(const float4*)(Wa + (size_t)(k + 0) * OUTC + cc);
    const float4 w1 = *(const float4*)(Wa + (size_t)(k + 1) * OUTC + cc);
    const float4 w2 = *(const float4*)(Wa + (size_t)(k + 2) * OUTC + cc);
    const float4 w3 = *(const float4*)(Wa + (size_t)(k + 3) * OUTC + cc);
#pragma unroll
    for (int r = 0; r < 4; ++r) {
      const float4 hv = *(const float4*)(h2 + (size_t)rowc[r] * HID + k);
      acc[r][0] += hv.x * w0.x + hv.y * w1.x + hv.z * w2.x + hv.w * w3.x;
      acc[r][1] += hv.x * w0.y + hv.y * w1.y + hv.z * w2.y + hv.w * w3.y;
      acc[r][2] += hv.x * w0.z + hv.y * w1.z + hv.z * w2.z + hv.w * w3.z;
      acc[r][3] += hv.x * w0.w + hv.y * w1.w + hv.z * w2.w + hv.w * w3.w;
    }
  }
  for (int k = 0; k < HID; k += 4) {
    const float4 w0 = *(const float4*)(Wb + (size_t)(k + 0) * OUTC + cc);
    const float4 w1 = *(const float4*)(Wb + (size_t)(k + 1) * OUTC + cc);
    const float4 w2 = *(const float4*)(Wb + (size_t)(k + 2) * OUTC + cc);
    const float4 w3 = *(const float4*)(Wb + (size_t)(k + 3) * OUTC + cc);
#pragma unroll
    for (int r = 0; r < 4; ++r) {
      const float4 hv = *(const float4*)(tx2 + (size_t)rowc[r] * HID + k);
      acc[r][0] += hv.x * w0.x + hv.y * w1.x + hv.z * w2.x + hv.w * w3.x;
      acc[r][1] += hv.x * w0.y + hv.y * w1.y + hv.z * w2.y + hv.w * w3.y;
      acc[r][2] += hv.x * w0.z + hv.y * w1.z + hv.z * w2.z + hv.w * w3.z;
      acc[r][3] += hv.x * w0.w + hv.y * w1.w + hv.z * w2.w + hv.w * w3.w;
    }
  }
#pragma unroll
  for (int r = 0; r < 4; ++r) {
    const int row = row0 + r;
    if (row < GN) {
      float4 o;
      o.x = acc[r][0] + bb[cc + 0];
      o.y = acc[r][1] + bb[cc + 1];
      o.z = acc[r][2] + bb[cc + 2];
      o.w = acc[r][3] + bb[cc + 3];
      *(float4*)(outp + (size_t)row * OUTC + cc) = o;
    }
  }
}

extern "C" void kernel_launch(void* const* d_in, const int* in_sizes, int n_in,
                              void* d_out, int out_size, void* d_ws, size_t ws_size,
                              hipStream_t stream) {
  (void)in_sizes; (void)n_in; (void)out_size; (void)ws_size;
  const float* x    = (const float*)d_in[0];
  const int*   ei   = (const int*)d_in[1];
  const float* Wt   = (const float*)d_in[2];
  const float* bt   = (const float*)d_in[3];
  const float* W0_1 = (const float*)d_in[4];
  const float* W1_1 = (const float*)d_in[5];
  const float* b1   = (const float*)d_in[6];
  const float* W0mu = (const float*)d_in[7];
  const float* W1mu = (const float*)d_in[8];
  const float* bmu  = (const float*)d_in[9];
  const float* W0ls = (const float*)d_in[10];
  const float* W1ls = (const float*)d_in[11];
  const float* bls  = (const float*)d_in[12];
  float* out = (float*)d_out;
  char* ws = (char*)d_ws;

  const int* src = ei;
  const int* dst = ei + GE;

  ushort_t* WtT  = (ushort_t*)(ws + OFF_WTT);
  float* P       = (float*)(ws + OFF_P);
  float* h       = (float*)(ws + OFF_H);
  float* tx1     = (float*)(ws + OFF_TX1);
  float* h2      = (float*)(ws + OFF_H2);
  float* tx2     = (float*)(ws + OFF_TX2);
  int* outdeg    = (int*)(ws + OFF_DEG);
  int* indeg     = (int*)(ws + OFF_INDEG);
  int* cursor    = (int*)(ws + OFF_CUR);
  int* row_ptr   = (int*)(ws + OFF_RP);
  float* dinv    = (float*)(ws + OFF_DINV);
  int* csr_src   = (int*)(ws + OFF_CSRC);
  float* csr_w   = (float*)(ws + OFF_CSW);

  zero_ints<<<120, 256, 0, stream>>>(outdeg);  // outdeg|indeg|cursor contiguous
  transpose_wt<<<dim3(313, 8), 256, 0, stream>>>(Wt, WtT);
  count_deg<<<GE / 256, 256, 0, stream>>>(src, dst, outdeg, indeg);
  dinv_kernel<<<40, 256, 0, stream>>>(outdeg, dinv);
  scan_kernel<<<1, 1024, 0, stream>>>(indeg, row_ptr);
  fill_csr<<<GE / 256, 256, 0, stream>>>(src, dst, dinv, row_ptr, cursor, csr_src, csr_w);
  gemm1_kernel<<<dim3(157, 4), 256, 0, stream>>>(x, WtT, P);
  combine_kernel<<<2500, 256, 0, stream>>>(P, bt, h);
  spmm_kernel<256, 1><<<GN, 256, 0, stream>>>(h, row_ptr, csr_src, csr_w, tx1);
  dense1_kernel<<<313, 256, 0, stream>>>(h, tx1, W0_1, W1_1, b1, h2);
  spmm_kernel<128, 2><<<GN / 2, 256, 0, stream>>>(h2, row_ptr, csr_src, csr_w, tx2);
  dense2_kernel<<<313, 256, 0, stream>>>(h2, tx2, W0mu, W1mu, bmu, W0ls, W1ls, bls, out);
}

// Round 2
// 959.150 us; speedup vs baseline: 1.0894x; 1.0894x over previous
//
#include <hip/hip_runtime.h>

typedef unsigned short ushort_t;
typedef __bf16 bf16x8 __attribute__((ext_vector_type(8)));
typedef float f32x4 __attribute__((ext_vector_type(4)));

#define GN 10000
#define GE 640000
#define INC 256
#define HID 128
#define OUTC 64

#define KP 10048        // padded K for WtT (zero-filled tail -> NaN-safe fragment reads)
#define SPLITK 8
#define KCHUNK 1280     // multiple of 64 so all fragment loads stay 16B-aligned

// ---------------- workspace layout (bytes, all 256-aligned; ws is ~1.6 GB) ----------------
constexpr size_t OFF_WTT   = 0;                                      // bf16 Wt^T [256][KP]
constexpr size_t OFF_P     = OFF_WTT + (size_t)256 * KP * 2;         // fp32 partials [8][10048][256]
constexpr size_t OFF_H     = OFF_P + (size_t)SPLITK * 10048 * 256 * 4; // fp32 h [10000][256]
constexpr size_t OFF_G1    = OFF_H + (size_t)GN * INC * 4;           // bf16 g1 = h@W1_1 [10000][128]
constexpr size_t OFF_TX1   = OFF_G1 + (size_t)GN * HID * 2;          // fp32 tx1w [10000][128]
constexpr size_t OFF_H2    = OFF_TX1 + (size_t)GN * HID * 4;         // fp32 h2 [10000][128]
constexpr size_t OFF_H2B   = OFF_H2 + (size_t)GN * HID * 4;          // bf16 h2 [10000][128]
constexpr size_t OFF_TX2   = OFF_H2B + (size_t)GN * HID * 2;         // fp32 tx2 [10000][128]
constexpr size_t OFF_DEG   = OFF_TX2 + (size_t)GN * HID * 4;         // int outdeg [10240]
constexpr size_t OFF_INDEG = OFF_DEG + 40960;
constexpr size_t OFF_CUR   = OFF_INDEG + 40960;
constexpr size_t OFF_RP    = OFF_CUR + 40960;
constexpr size_t OFF_DINV  = OFF_RP + 40960;
constexpr size_t OFF_CSRC  = OFF_DINV + 40960;                       // int csr_src [E]
constexpr size_t OFF_CSW   = OFF_CSRC + (size_t)GE * 4;              // float csr_w [E]
// total ~124 MB

__device__ __forceinline__ ushort_t f2bf(float f) {
  unsigned int u = __float_as_uint(f);
  u += 0x7fffu + ((u >> 16) & 1u);   // RNE
  return (ushort_t)(u >> 16);
}
__device__ __forceinline__ float bf_lo(unsigned int p) { return __uint_as_float(p << 16); }
__device__ __forceinline__ float bf_hi(unsigned int p) { return __uint_as_float(p & 0xffff0000u); }

// ---------------- zero the three atomic-counter arrays ----------------
__global__ __launch_bounds__(256) void zero_ints(int* __restrict__ p) {
  p[blockIdx.x * 256 + threadIdx.x] = 0;   // 30720 ints: outdeg|indeg|cursor
}

// ---------------- Wt [10000][256] f32 -> Wt^T [256][KP] bf16 (zero pad k>=GN) ----------------
__global__ __launch_bounds__(256) void transpose_wt(const float* __restrict__ Wt,
                                                    ushort_t* __restrict__ WtT) {
  __shared__ float tile[32][33];
  const int tx = threadIdx.x & 31, ty = threadIdx.x >> 5;   // 32 x 8
  const int k0 = blockIdx.x * 32, c0 = blockIdx.y * 32;
#pragma unroll
  for (int j = 0; j < 4; ++j) {
    const int k = k0 + ty + j * 8;
    tile[ty + j * 8][tx] = (k < GN) ? Wt[(size_t)k * INC + c0 + tx] : 0.f;
  }
  __syncthreads();
#pragma unroll
  for (int j = 0; j < 4; ++j) {
    const int c = c0 + ty + j * 8;
    const int k = k0 + tx;
    WtT[(size_t)c * KP + k] = f2bf(tile[tx][ty + j * 8]);
  }
}

// ---------------- degree counts ----------------
__global__ __launch_bounds__(256) void count_deg(const int* __restrict__ src,
                                                 const int* __restrict__ dst,
                                                 int* __restrict__ outdeg,
                                                 int* __restrict__ indeg) {
  const int e = blockIdx.x * 256 + threadIdx.x;
  atomicAdd(&outdeg[src[e]], 1);
  atomicAdd(&indeg[dst[e]], 1);
}

__global__ __launch_bounds__(256) void dinv_kernel(const int* __restrict__ outdeg,
                                                   float* __restrict__ dinv) {
  const int i = blockIdx.x * 256 + threadIdx.x;
  if (i < GN) {
    const int d = outdeg[i];
    dinv[i] = (d > 0) ? rsqrtf((float)d) : 0.f;
  }
}

// ---------------- exclusive scan of indeg -> row_ptr[0..10000] ----------------
__global__ __launch_bounds__(1024) void scan_kernel(const int* __restrict__ indeg,
                                                    int* __restrict__ row_ptr) {
  __shared__ int sdata[1024];
  const int t = threadIdx.x;
  const int base = t * 10;
  int loc[10];
  int s = 0;
#pragma unroll
  for (int j = 0; j < 10; ++j) {
    const int idx = base + j;
    const int v = (idx < GN) ? indeg[idx] : 0;
    loc[j] = v;
    s += v;
  }
  sdata[t] = s;
  __syncthreads();
  for (int off = 1; off < 1024; off <<= 1) {
    int v = 0;
    if (t >= off) v = sdata[t - off];
    __syncthreads();
    if (t >= off) sdata[t] += v;
    __syncthreads();
  }
  int run = sdata[t] - s;   // exclusive prefix
#pragma unroll
  for (int j = 0; j < 10; ++j) {
    const int idx = base + j;
    if (idx <= GN) row_ptr[idx] = run;
    if (idx < GN) run += loc[j];
  }
}

// ---------------- CSR fill (by dst) ----------------
__global__ __launch_bounds__(256) void fill_csr(const int* __restrict__ src,
                                                const int* __restrict__ dst,
                                                const float* __restrict__ dinv,
                                                const int* __restrict__ row_ptr,
                                                int* __restrict__ cursor,
                                                int* __restrict__ csr_src,
                                                float* __restrict__ csr_w) {
  const int e = blockIdx.x * 256 + threadIdx.x;
  const int s = src[e];
  const int d = dst[e];
  const float w = -dinv[s] * dinv[d];
  const int pos = atomicAdd(&cursor[d], 1);
  const int slot = row_ptr[d] + pos;
  csr_src[slot] = s;
  csr_w[slot] = w;
}

// ---------------- GEMM1: P[ks] = x[:, kslice] @ Wt[kslice, :]  (bf16 MFMA) ----------------
// grid (157, 8), block 256 (4 waves). Tile BM=64 x BN=256, BK=64.
// A double-buffered in LDS (18.4 KB, ONE barrier/iter); B-frags read direct from
// L2-resident WtT (k-contiguous 16B/lane). ~3 blocks/CU resident hide the barrier drain.
__global__ __launch_bounds__(256, 3) void gemm1_kernel(const float* __restrict__ x,
                                                       const ushort_t* __restrict__ WtT,
                                                       float* __restrict__ P) {
  constexpr int LDK = 72;   // bf16 pad: row stride 144B -> 2-lane/bank (free) on frag reads
  __shared__ __align__(16) ushort_t As[2][64 * LDK];
  const int t = threadIdx.x;
  const int wave = t >> 6, lane = t & 63;
  const int m16 = lane & 15, quad = lane >> 4;
  const int rowbase = blockIdx.x * 64;
  const int ks = blockIdx.y;
  const int kbeg = ks * KCHUNK;
  const int kend = min(kbeg + KCHUNK, GN);
  const int nit = (kend - kbeg + 63) >> 6;
  const int col0 = wave * 64;

  const int ar = t >> 4;           // 0..15 (A row within 16-row group)
  const int ak = (t & 15) << 2;    // 0..60 (A k offset, float4)

  f32x4 acc[4][4];
#pragma unroll
  for (int i = 0; i < 4; ++i)
#pragma unroll
    for (int j = 0; j < 4; ++j) acc[i][j] = {0.f, 0.f, 0.f, 0.f};

  float4 va[4];
  // prologue: load A tile for it=0 (kend,ak multiples of 4 -> float4 never straddles kend)
  {
    const int gk = kbeg + ak;
#pragma unroll
    for (int i = 0; i < 4; ++i) {
      const int row = rowbase + ar + i * 16;
      float4 r = make_float4(0.f, 0.f, 0.f, 0.f);
      if (row < GN && gk < kend) r = *(const float4*)(x + (size_t)row * GN + gk);
      va[i] = r;
    }
  }

#pragma unroll 2
  for (int it = 0; it < nit; ++it) {
    ushort_t* Ab = &As[it & 1][0];
    // convert + stage current A tile
#pragma unroll
    for (int i = 0; i < 4; ++i) {
      ushort4 o = make_ushort4(f2bf(va[i].x), f2bf(va[i].y), f2bf(va[i].z), f2bf(va[i].w));
      *reinterpret_cast<ushort4*>(&Ab[(ar + i * 16) * LDK + ak]) = o;
    }
    // prefetch next A tile (in flight across the barrier)
    float4 vb[4] = {};
    if (it + 1 < nit) {
      const int gk = kbeg + ((it + 1) << 6) + ak;
#pragma unroll
      for (int i = 0; i < 4; ++i) {
        const int row = rowbase + ar + i * 16;
        float4 r = make_float4(0.f, 0.f, 0.f, 0.f);
        if (row < GN && gk < kend) r = *(const float4*)(x + (size_t)row * GN + gk);
        vb[i] = r;
      }
    }
    __syncthreads();   // single barrier per iter (double buffer makes trailing barrier unnecessary)
    const int k0 = kbeg + (it << 6);
#pragma unroll
    for (int hh = 0; hh < 2; ++hh) {
      const int kk = hh * 32 + quad * 8;
      bf16x8 a[4], b[4];
#pragma unroll
      for (int ni = 0; ni < 4; ++ni)
        b[ni] = *reinterpret_cast<const bf16x8*>(WtT + (size_t)(col0 + ni * 16 + m16) * KP + k0 + kk);
#pragma unroll
      for (int mi = 0; mi < 4; ++mi)
        a[mi] = *reinterpret_cast<const bf16x8*>(&Ab[(mi * 16 + m16) * LDK + kk]);
#pragma unroll
      for (int mi = 0; mi < 4; ++mi)
#pragma unroll
        for (int ni = 0; ni < 4; ++ni)
          acc[mi][ni] = __builtin_amdgcn_mfma_f32_16x16x32_bf16(a[mi], b[ni], acc[mi][ni], 0, 0, 0);
    }
#pragma unroll
    for (int i = 0; i < 4; ++i) va[i] = vb[i];
  }
  // store partial tile: C layout col=lane&15, row=quad*4+reg
#pragma unroll
  for (int mi = 0; mi < 4; ++mi)
#pragma unroll
    for (int ni = 0; ni < 4; ++ni) {
      const int col = col0 + ni * 16 + m16;
      const int row0 = rowbase + mi * 16 + quad * 4;
      float* p = P + ((size_t)ks * 10048 + row0) * 256 + col;
#pragma unroll
      for (int r = 0; r < 4; ++r) p[(size_t)r * 256] = acc[mi][ni][r];
    }
}

// ---------------- combine 8 split-K partials + bias + relu -> h ----------------
__global__ __launch_bounds__(256) void combine_kernel(const float* __restrict__ P,
                                                      const float* __restrict__ bt,
                                                      float* __restrict__ h) {
  const int tid = blockIdx.x * 256 + threadIdx.x;
  const int i = tid >> 6;
  const int c = (tid & 63) << 2;
  const size_t stride = (size_t)10048 * 256;
  const size_t base = (size_t)i * 256 + c;
  float4 s = *(const float4*)(P + base);
#pragma unroll
  for (int k = 1; k < SPLITK; ++k) {
    const float4 p = *(const float4*)(P + (size_t)k * stride + base);
    s.x += p.x; s.y += p.y; s.z += p.z; s.w += p.w;
  }
  const float4 bv = *(const float4*)(bt + c);
  float4 o;
  o.x = fmaxf(s.x + bv.x, 0.f);
  o.y = fmaxf(s.y + bv.y, 0.f);
  o.z = fmaxf(s.z + bv.z, 0.f);
  o.w = fmaxf(s.w + bv.w, 0.f);
  *(float4*)(h + base) = o;
}

// ---------------- g1 = h @ W1_1 -> bf16 [10000][128] (gather operand for spmm1) ----------------
__global__ __launch_bounds__(256) void dense_g1_kernel(const float* __restrict__ h,
                                                       const float* __restrict__ W1,
                                                       ushort_t* __restrict__ g1) {
  const int t = threadIdx.x;
  const int cq = (t & 31) << 2;            // 0..124
  const int rq = t >> 5;                   // 0..7
  const int row0 = blockIdx.x * 32 + rq * 4;
  int rowc[4];
#pragma unroll
  for (int r = 0; r < 4; ++r) rowc[r] = min(row0 + r, GN - 1);
  float acc[4][4] = {};
  for (int k = 0; k < INC; k += 4) {
    const float4 w0 = *(const float4*)(W1 + (size_t)(k + 0) * HID + cq);
    const float4 w1 = *(const float4*)(W1 + (size_t)(k + 1) * HID + cq);
    const float4 w2 = *(const float4*)(W1 + (size_t)(k + 2) * HID + cq);
    const float4 w3 = *(const float4*)(W1 + (size_t)(k + 3) * HID + cq);
#pragma unroll
    for (int r = 0; r < 4; ++r) {
      const float4 hv = *(const float4*)(h + (size_t)rowc[r] * INC + k);
      acc[r][0] += hv.x * w0.x + hv.y * w1.x + hv.z * w2.x + hv.w * w3.x;
      acc[r][1] += hv.x * w0.y + hv.y * w1.y + hv.z * w2.y + hv.w * w3.y;
      acc[r][2] += hv.x * w0.z + hv.y * w1.z + hv.z * w2.z + hv.w * w3.z;
      acc[r][3] += hv.x * w0.w + hv.y * w1.w + hv.z * w2.w + hv.w * w3.w;
    }
  }
#pragma unroll
  for (int r = 0; r < 4; ++r) {
    const int row = row0 + r;
    if (row < GN) {
      ushort4 o = make_ushort4(f2bf(acc[r][0]), f2bf(acc[r][1]), f2bf(acc[r][2]), f2bf(acc[r][3]));
      *reinterpret_cast<ushort4*>(g1 + (size_t)row * HID + cq) = o;
    }
  }
}

// ---------------- SpMM (bf16 gather, C=128): tx[d] = sum w_e * g[src_e] ----------------
// block 256 = 4 nodes x 64 lanes; lane handles 2 channels via one u32 (bf16x2) load.
__global__ __launch_bounds__(256) void spmm_bf16(const unsigned int* __restrict__ g,
                                                 const int* __restrict__ row_ptr,
                                                 const int* __restrict__ csr_src,
                                                 const float* __restrict__ csr_w,
                                                 float* __restrict__ tx) {
  const int t = threadIdx.x;
  const int node = blockIdx.x * 4 + (t >> 6);
  const int lane = t & 63;
  const int beg = row_ptr[node];
  const int end = row_ptr[node + 1];
  float a0 = 0.f, a1 = 0.f;
  int j = beg;
  for (; j + 1 < end; j += 2) {
    const int s0 = csr_src[j];
    const int s1 = csr_src[j + 1];
    const float w0 = csr_w[j];
    const float w1 = csr_w[j + 1];
    const unsigned int p0 = g[(size_t)s0 * 64 + lane];
    const unsigned int p1 = g[(size_t)s1 * 64 + lane];
    a0 = fmaf(w0, bf_lo(p0), a0);
    a1 = fmaf(w0, bf_hi(p0), a1);
    a0 = fmaf(w1, bf_lo(p1), a0);
    a1 = fmaf(w1, bf_hi(p1), a1);
  }
  if (j < end) {
    const int s0 = csr_src[j];
    const float w0 = csr_w[j];
    const unsigned int p0 = g[(size_t)s0 * 64 + lane];
    a0 = fmaf(w0, bf_lo(p0), a0);
    a1 = fmaf(w0, bf_hi(p0), a1);
  }
  float2 o = make_float2(a0, a1);
  *(float2*)(tx + (size_t)node * HID + lane * 2) = o;
}

// ---------------- dense1: h2 = relu(h@W0_1 + tx1w + b1); emit fp32 + bf16 ----------------
__global__ __launch_bounds__(256) void dense1_kernel(const float* __restrict__ h,
                                                     const float* __restrict__ tx,
                                                     const float* __restrict__ W0,
                                                     const float* __restrict__ b,
                                                     float* __restrict__ h2,
                                                     ushort_t* __restrict__ h2b) {
  const int t = threadIdx.x;
  const int cq = (t & 31) << 2;            // 0..124
  const int rq = t >> 5;                   // 0..7
  const int row0 = blockIdx.x * 32 + rq * 4;
  int rowc[4];
#pragma unroll
  for (int r = 0; r < 4; ++r) rowc[r] = min(row0 + r, GN - 1);
  float acc[4][4] = {};
  for (int k = 0; k < INC; k += 4) {
    const float4 w0 = *(const float4*)(W0 + (size_t)(k + 0) * HID + cq);
    const float4 w1 = *(const float4*)(W0 + (size_t)(k + 1) * HID + cq);
    const float4 w2 = *(const float4*)(W0 + (size_t)(k + 2) * HID + cq);
    const float4 w3 = *(const float4*)(W0 + (size_t)(k + 3) * HID + cq);
#pragma unroll
    for (int r = 0; r < 4; ++r) {
      const float4 hv = *(const float4*)(h + (size_t)rowc[r] * INC + k);
      acc[r][0] += hv.x * w0.x + hv.y * w1.x + hv.z * w2.x + hv.w * w3.x;
      acc[r][1] += hv.x * w0.y + hv.y * w1.y + hv.z * w2.y + hv.w * w3.y;
      acc[r][2] += hv.x * w0.z + hv.y * w1.z + hv.z * w2.z + hv.w * w3.z;
      acc[r][3] += hv.x * w0.w + hv.y * w1.w + hv.z * w2.w + hv.w * w3.w;
    }
  }
  const float4 bv = *(const float4*)(b + cq);
#pragma unroll
  for (int r = 0; r < 4; ++r) {
    const int row = row0 + r;
    if (row < GN) {
      const float4 tv = *(const float4*)(tx + (size_t)row * HID + cq);
      float4 o;
      o.x = fmaxf(acc[r][0] + tv.x + bv.x, 0.f);
      o.y = fmaxf(acc[r][1] + tv.y + bv.y, 0.f);
      o.z = fmaxf(acc[r][2] + tv.z + bv.z, 0.f);
      o.w = fmaxf(acc[r][3] + tv.w + bv.w, 0.f);
      *(float4*)(h2 + (size_t)row * HID + cq) = o;
      ushort4 ob = make_ushort4(f2bf(o.x), f2bf(o.y), f2bf(o.z), f2bf(o.w));
      *reinterpret_cast<ushort4*>(h2b + (size_t)row * HID + cq) = ob;
    }
  }
}

// ---------------- dense2 (mu & logstd fused): out = [h2@W0+tx2@W1+b] x2 ----------------
__global__ __launch_bounds__(256) void dense2_kernel(const float* __restrict__ h2,
                                                     const float* __restrict__ tx2,
                                                     const float* __restrict__ W0mu,
                                                     const float* __restrict__ W1mu,
                                                     const float* __restrict__ bmu,
                                                     const float* __restrict__ W0ls,
                                                     const float* __restrict__ W1ls,
                                                     const float* __restrict__ bls,
                                                     float* __restrict__ out) {
  const int t = threadIdx.x;
  const int cq = (t & 31) << 2;           // 0..124 across [mu(64) | ls(64)]
  const int rq = t >> 5;
  const int row0 = blockIdx.x * 32 + rq * 4;
  const bool is_mu = (cq < OUTC);
  const int cc = cq & (OUTC - 1);
  const float* Wa = is_mu ? W0mu : W0ls;
  const float* Wb = is_mu ? W1mu : W1ls;
  const float* bb = is_mu ? bmu : bls;
  float* outp = out + (is_mu ? (size_t)0 : (size_t)GN * OUTC);
  int rowc[4];
#pragma unroll
  for (int r = 0; r < 4; ++r) rowc[r] = min(row0 + r, GN - 1);
  float acc[4][4] = {};
  for (int k = 0; k < HID; k += 4) {
    const float4 w0 = *(const float4*)(Wa + (size_t)(k + 0) * OUTC + cc);
    const float4 w1 = *(const float4*)(Wa + (size_t)(k + 1) * OUTC + cc);
    const float4 w2 = *(const float4*)(Wa + (size_t)(k + 2) * OUTC + cc);
    const float4 w3 = *(const float4*)(Wa + (size_t)(k + 3) * OUTC + cc);
#pragma unroll
    for (int r = 0; r < 4; ++r) {
      const float4 hv = *(const float4*)(h2 + (size_t)rowc[r] * HID + k);
      acc[r][0] += hv.x * w0.x + hv.y * w1.x + hv.z * w2.x + hv.w * w3.x;
      acc[r][1] += hv.x * w0.y + hv.y * w1.y + hv.z * w2.y + hv.w * w3.y;
      acc[r][2] += hv.x * w0.z + hv.y * w1.z + hv.z * w2.z + hv.w * w3.z;
      acc[r][3] += hv.x * w0.w + hv.y * w1.w + hv.z * w2.w + hv.w * w3.w;
    }
  }
  for (int k = 0; k < HID; k += 4) {
    const float4 w0 = *(const float4*)(Wb + (size_t)(k + 0) * OUTC + cc);
    const float4 w1 = *(const float4*)(Wb + (size_t)(k + 1) * OUTC + cc);
    const float4 w2 = *(const float4*)(Wb + (size_t)(k + 2) * OUTC + cc);
    const float4 w3 = *(const float4*)(Wb + (size_t)(k + 3) * OUTC + cc);
#pragma unroll
    for (int r = 0; r < 4; ++r) {
      const float4 hv = *(const float4*)(tx2 + (size_t)rowc[r] * HID + k);
      acc[r][0] += hv.x * w0.x + hv.y * w1.x + hv.z * w2.x + hv.w * w3.x;
      acc[r][1] += hv.x * w0.y + hv.y * w1.y + hv.z * w2.y + hv.w * w3.y;
      acc[r][2] += hv.x * w0.z + hv.y * w1.z + hv.z * w2.z + hv.w * w3.z;
      acc[r][3] += hv.x * w0.w + hv.y * w1.w + hv.z * w2.w + hv.w * w3.w;
    }
  }
#pragma unroll
  for (int r = 0; r < 4; ++r) {
    const int row = row0 + r;
    if (row < GN) {
      float4 o;
      o.x = acc[r][0] + bb[cc + 0];
      o.y = acc[r][1] + bb[cc + 1];
      o.z = acc[r][2] + bb[cc + 2];
      o.w = acc[r][3] + bb[cc + 3];
      *(float4*)(outp + (size_t)row * OUTC + cc) = o;
    }
  }
}

extern "C" void kernel_launch(void* const* d_in, const int* in_sizes, int n_in,
                              void* d_out, int out_size, void* d_ws, size_t ws_size,
                              hipStream_t stream) {
  (void)in_sizes; (void)n_in; (void)out_size; (void)ws_size;
  const float* x    = (const float*)d_in[0];
  const int*   ei   = (const int*)d_in[1];
  const float* Wt   = (const float*)d_in[2];
  const float* bt   = (const float*)d_in[3];
  const float* W0_1 = (const float*)d_in[4];
  const float* W1_1 = (const float*)d_in[5];
  const float* b1   = (const float*)d_in[6];
  const float* W0mu = (const float*)d_in[7];
  const float* W1mu = (const float*)d_in[8];
  const float* bmu  = (const float*)d_in[9];
  const float* W0ls = (const float*)d_in[10];
  const float* W1ls = (const float*)d_in[11];
  const float* bls  = (const float*)d_in[12];
  float* out = (float*)d_out;
  char* ws = (char*)d_ws;

  const int* src = ei;
  const int* dst = ei + GE;

  ushort_t* WtT  = (ushort_t*)(ws + OFF_WTT);
  float* P       = (float*)(ws + OFF_P);
  float* h       = (float*)(ws + OFF_H);
  ushort_t* g1   = (ushort_t*)(ws + OFF_G1);
  float* tx1w    = (float*)(ws + OFF_TX1);
  float* h2      = (float*)(ws + OFF_H2);
  ushort_t* h2b  = (ushort_t*)(ws + OFF_H2B);
  float* tx2     = (float*)(ws + OFF_TX2);
  int* outdeg    = (int*)(ws + OFF_DEG);
  int* indeg     = (int*)(ws + OFF_INDEG);
  int* cursor    = (int*)(ws + OFF_CUR);
  int* row_ptr   = (int*)(ws + OFF_RP);
  float* dinv    = (float*)(ws + OFF_DINV);
  int* csr_src   = (int*)(ws + OFF_CSRC);
  float* csr_w   = (float*)(ws + OFF_CSW);

  zero_ints<<<120, 256, 0, stream>>>(outdeg);  // outdeg|indeg|cursor contiguous
  transpose_wt<<<dim3(KP / 32, 8), 256, 0, stream>>>(Wt, WtT);
  count_deg<<<GE / 256, 256, 0, stream>>>(src, dst, outdeg, indeg);
  dinv_kernel<<<40, 256, 0, stream>>>(outdeg, dinv);
  scan_kernel<<<1, 1024, 0, stream>>>(indeg, row_ptr);
  fill_csr<<<GE / 256, 256, 0, stream>>>(src, dst, dinv, row_ptr, cursor, csr_src, csr_w);
  gemm1_kernel<<<dim3(157, SPLITK), 256, 0, stream>>>(x, WtT, P);
  combine_kernel<<<2500, 256, 0, stream>>>(P, bt, h);
  dense_g1_kernel<<<313, 256, 0, stream>>>(h, W1_1, g1);
  spmm_bf16<<<2500, 256, 0, stream>>>((const unsigned int*)g1, row_ptr, csr_src, csr_w, tx1w);
  dense1_kernel<<<313, 256, 0, stream>>>(h, tx1w, W0_1, b1, h2, h2b);
  spmm_bf16<<<2500, 256, 0, stream>>>((const unsigned int*)h2b, row_ptr, csr_src, csr_w, tx2);
  dense2_kernel<<<313, 256, 0, stream>>>(h2, tx2, W0mu, W1mu, bmu, W0ls, W1ls, bls, out);
}